// Round 7
// baseline (364.933 us; speedup 1.0000x reference)
//
#include <hip/hip_runtime.h>

#define NTOK 16384
#define CDIM 256
#define INNER 1024
#define WW 128
#define HH 128

typedef unsigned short bf16_t;
typedef __bf16 bf16x8 __attribute__((ext_vector_type(8)));
typedef float f32x4 __attribute__((ext_vector_type(4)));

__device__ __forceinline__ float bf2f(bf16_t u) {
    union { unsigned int i; float f; } x;
    x.i = ((unsigned int)u) << 16;
    return x.f;
}
__device__ __forceinline__ bf16_t f2bf(float f) {
    union { float f; unsigned int i; } x;
    x.f = f;
    unsigned int r = x.i + 0x7FFFu + ((x.i >> 16) & 1u);
    return (bf16_t)(r >> 16);
}
// pack two f32 -> u32 of 2 bf16 (RNE), T12 recipe (no builtin on gfx950)
__device__ __forceinline__ unsigned int cvtpk(float a, float b) {
    unsigned int r;
    asm("v_cvt_pk_bf16_f32 %0, %1, %2" : "=v"(r) : "v"(a), "v"(b));
    return r;
}

// workspace byte offsets (round-3 layout; xn/outc regions unused)
static const size_t OFF_VT   = 16777216;   // bf16 [2][16384][1024] (written directly by k12)
static const size_t OFF_XO   = 83886080;   // bf16 [2][1024][16384]
static const size_t OFF_VP   = 150994944;
static const size_t OFF_PE2  = 184549376;
static const size_t OFF_WBF  = 201326592;
static const size_t OFF_S    = 218103808;  // f32 [2][16][64][64]; attn bf16 in-place after k3
static const size_t OFF_SSQ  = 218628096;
static const size_t OFF_SSK  = 218636288;

// ---------------- K12: fused conv3x3+BN (q,k,v) + Gram MFMA + direct vt emit ----------------
// v7 = round-3 proven structure (8-row chunks, split-K atomics, 104 us) + PIPELINED STAGING:
// the grid is exactly 2 blocks/CU (phase-aligned), so v3's monolithic tap staging serializes
// a ~40us grid-wide fetch burst before any compute. Now: stage rows 0..2 up front; rows 3..9
// are prefetched one per kc-pair (issue global->reg at even step top, LDS-commit in the odd
// step between barriers, consumed a pair later). T14 issue-early/write-late; the compiler's
// auto vmcnt on the prefetch regs is 1-deep (vt store stays in flight).
__global__ __launch_bounds__(512, 4) void k12_fused(
    const float* __restrict__ x,
    const float* __restrict__ wq, const float* __restrict__ wk, const float* __restrict__ wv,
    const float* __restrict__ qg, const float* __restrict__ qb, const float* __restrict__ qm, const float* __restrict__ qv,
    const float* __restrict__ kg, const float* __restrict__ kb, const float* __restrict__ km, const float* __restrict__ kv_,
    const float* __restrict__ vg, const float* __restrict__ vb, const float* __restrict__ vm, const float* __restrict__ vv,
    bf16_t* __restrict__ vt, float* __restrict__ S,
    float* __restrict__ ssq, float* __restrict__ ssk) {
    int chunk = blockIdx.x;   // 0..15 (8 image rows each)
    int h = blockIdx.y;       // 0..15
    int b = blockIdx.z;
    int y0 = chunk * 8;

    __shared__ ushort taps[16][10][132];      // 42,240 B (plane pp, gy=y0-1+i, gx=c-1)
    __shared__ ushort Qs[64][72];             // 9,216 B
    __shared__ ushort Ks[64][72];             // 9,216 B
    __shared__ unsigned int Vs32[64][34];     // 8,704 B

    int tid = threadIdx.x;
    int lane = tid & 63, wave = tid >> 6;
    const float* xb = x + (size_t)b * NTOK * CDIM + h * 16;

    // ---- prologue: stage tap rows 0..2 only (390 positions x 4 quads) ----
    for (int u = tid; u < 1560; u += 512) {
        int pos = u >> 2, quad = u & 3;
        int i = pos / 130, c = pos - i * 130;
        int gy = y0 - 1 + i, gx = c - 1;
        if (gy >= 0 && gy < HH && gx >= 0 && gx < WW) {
            float4 v = *(const float4*)&xb[(size_t)(gy * WW + gx) * CDIM + quad * 4];
            taps[quad * 4 + 0][i][c] = f2bf(v.x);
            taps[quad * 4 + 1][i][c] = f2bf(v.y);
            taps[quad * 4 + 2][i][c] = f2bf(v.z);
            taps[quad * 4 + 3][i][c] = f2bf(v.w);
        } else {
            taps[quad * 4 + 0][i][c] = 0;
            taps[quad * 4 + 1][i][c] = 0;
            taps[quad * 4 + 2][i][c] = 0;
            taps[quad * 4 + 3][i][c] = 0;
        }
    }

    // ---- per-thread roles ----
    int tq = tid & 15;          // token quad: 4 tokens x0..x0+3
    int pc = (tid >> 4) & 15;   // input plane (0..15) -> 4 output channels
    int ts = tid >> 8;          // 0: q-tensor, 1: k-tensor (wave-uniform)

    // ---- preload folded weights: q-or-k (4 ch) and v half (2 ch) ----
    const float* wsrc = ts ? wk : wq;
    const float* gp = ts ? kg : qg;
    const float* bp = ts ? kb : qb;
    const float* mp = ts ? km : qm;
    const float* vp_ = ts ? kv_ : qv;
    int chbase = h * 64 + pc * 4;
    float wQK[4][9], shQK[4];
#pragma unroll
    for (int s = 0; s < 4; s++) {
        int ch = chbase + s;
        float sc = gp[ch] * rsqrtf(vp_[ch] + 1e-5f);
        shQK[s] = bp[ch] - mp[ch] * sc;
#pragma unroll
        for (int t = 0; t < 9; t++) wQK[s][t] = wsrc[(size_t)ch * 9 + t] * sc;
    }
    float wV[2][9], shV[2];
#pragma unroll
    for (int sv = 0; sv < 2; sv++) {
        int ch = chbase + 2 * ts + sv;
        float sc = vg[ch] * rsqrtf(vv[ch] + 1e-5f);
        shV[sv] = vb[ch] - vm[ch] * sc;
#pragma unroll
        for (int t = 0; t < 9; t++) wV[sv][t] = wv[(size_t)ch * 9 + t] * sc;
    }

    ushort (*QK)[72] = ts ? Ks : Qs;

    // MFMA partition (proven k2 pattern, 8-wave split)
    int wm = wave & 1;          // d half (32)
    int wn4 = wave >> 1;        // e quarter (16)
    int qd = lane >> 4, l16 = lane & 15;
    f32x4 acc[2];
    acc[0] = (f32x4){0.f, 0.f, 0.f, 0.f};
    acc[1] = (f32x4){0.f, 0.f, 0.f, 0.f};

    // vt store role
    int vrow = tid >> 3;        // t_local 0..63
    int vseg = tid & 7;         // 8-ch segment
    bf16_t* vtb = vt + (size_t)b * 16777216 + (size_t)h * 64;

    // row-prefetch thread mapping: unit0 = tid -> (col tid>>2, quad tid&3);
    // unit1 = 512+tid (tid<8) -> col 128+(tid>>2), quad tid&3; col 129 (gx=128) is OOB -> zero
    float4 pf0 = {0.f, 0.f, 0.f, 0.f};
    float4 pf1 = {0.f, 0.f, 0.f, 0.f};
    int pcc0 = tid >> 2, pq = tid & 3;

    float ssl[4] = {0.f, 0.f, 0.f, 0.f};

    __syncthreads();   // prologue taps visible

#pragma unroll 1
    for (int kc = 0; kc < 1024; kc += 64) {
        int grp = kc >> 6;
        int ly = grp >> 1;              // local output row 0..7
        int xh = (grp & 1) << 6;        // 0 or 64
        int x0 = xh + tq * 4;
        int even = ((grp & 1) == 0);
        int pr = ly + 3;                // prefetch row for this pair

        // issue prefetch loads for row pr at top of even step (flight time ~2 phases)
        if (even && pr < 10) {
            int gy = y0 - 1 + pr;       // >= 2 always
            pf0 = (float4){0.f, 0.f, 0.f, 0.f};
            pf1 = (float4){0.f, 0.f, 0.f, 0.f};
            int gxa = pcc0 - 1;
            if (gy < HH && gxa >= 0)
                pf0 = *(const float4*)&xb[(size_t)(gy * WW + gxa) * CDIM + pq * 4];
            if (tid < 4 && gy < HH)     // unit1 col 128 -> gx 127; col 129 OOB stays zero
                pf1 = *(const float4*)&xb[(size_t)(gy * WW + 127) * CDIM + pq * 4];
        }

        // tap window rows ly..ly+2, cols x0..x0+5 of plane pc
        float tp[3][6];
#pragma unroll
        for (int i = 0; i < 3; i++) {
            const ushort* rp = &taps[pc][ly + i][x0];
            ushort4 u4 = *(const ushort4*)rp;
            ushort2 u2 = *(const ushort2*)(rp + 4);
            tp[i][0] = bf2f(u4.x); tp[i][1] = bf2f(u4.y);
            tp[i][2] = bf2f(u4.z); tp[i][3] = bf2f(u4.w);
            tp[i][4] = bf2f(u2.x); tp[i][5] = bf2f(u2.y);
        }

        // q-or-k: 4 channels x 4 tokens
#pragma unroll
        for (int s = 0; s < 4; s++) {
            float o0 = shQK[s], o1 = shQK[s], o2 = shQK[s], o3 = shQK[s];
#pragma unroll
            for (int i = 0; i < 3; i++) {
                float wa = wQK[s][i * 3 + 0], wb = wQK[s][i * 3 + 1], wc = wQK[s][i * 3 + 2];
                o0 += wa * tp[i][0] + wb * tp[i][1] + wc * tp[i][2];
                o1 += wa * tp[i][1] + wb * tp[i][2] + wc * tp[i][3];
                o2 += wa * tp[i][2] + wb * tp[i][3] + wc * tp[i][4];
                o3 += wa * tp[i][3] + wb * tp[i][4] + wc * tp[i][5];
            }
            ssl[s] += o0 * o0 + o1 * o1 + o2 * o2 + o3 * o3;
            uint2 pk;
            pk.x = cvtpk(o0, o1);
            pk.y = cvtpk(o2, o3);
            *(uint2*)&QK[pc * 4 + s][tq * 4] = pk;
        }

        // v: 2 channels (pair pc*2+ts) x 4 tokens
        {
            float ov[2][4];
#pragma unroll
            for (int sv = 0; sv < 2; sv++) {
                float o0 = shV[sv], o1 = shV[sv], o2 = shV[sv], o3 = shV[sv];
#pragma unroll
                for (int i = 0; i < 3; i++) {
                    float wa = wV[sv][i * 3 + 0], wb = wV[sv][i * 3 + 1], wc = wV[sv][i * 3 + 2];
                    o0 += wa * tp[i][0] + wb * tp[i][1] + wc * tp[i][2];
                    o1 += wa * tp[i][1] + wb * tp[i][2] + wc * tp[i][3];
                    o2 += wa * tp[i][2] + wb * tp[i][3] + wc * tp[i][4];
                    o3 += wa * tp[i][3] + wb * tp[i][4] + wc * tp[i][5];
                }
                ov[sv][0] = o0; ov[sv][1] = o1; ov[sv][2] = o2; ov[sv][3] = o3;
            }
#pragma unroll
            for (int j = 0; j < 4; j++)
                Vs32[tq * 4 + j][pc * 2 + ts] = cvtpk(ov[0][j], ov[1][j]);
        }

        // my LDS writes done, then barrier (B1) — no vmcnt drain (r6: drain was free anyway)
        asm volatile("s_waitcnt lgkmcnt(0)" ::: "memory");
        __builtin_amdgcn_s_barrier();

        // commit prefetched row pr in the odd step (consumed at pair ly+1, after B2)
        if (!even && pr < 10) {
            taps[pq * 4 + 0][pr][pcc0] = f2bf(pf0.x);
            taps[pq * 4 + 1][pr][pcc0] = f2bf(pf0.y);
            taps[pq * 4 + 2][pr][pcc0] = f2bf(pf0.z);
            taps[pq * 4 + 3][pr][pcc0] = f2bf(pf0.w);
            if (tid < 8) {
                int cc2 = 128 + (tid >> 2);
                taps[pq * 4 + 0][pr][cc2] = f2bf(pf1.x);
                taps[pq * 4 + 1][pr][cc2] = f2bf(pf1.y);
                taps[pq * 4 + 2][pr][cc2] = f2bf(pf1.z);
                taps[pq * 4 + 3][pr][cc2] = f2bf(pf1.w);
            }
        }

        // vt emit: global store stays in flight across barriers
        {
            uint4 o4;
            o4.x = Vs32[vrow][vseg * 4 + 0];
            o4.y = Vs32[vrow][vseg * 4 + 1];
            o4.z = Vs32[vrow][vseg * 4 + 2];
            o4.w = Vs32[vrow][vseg * 4 + 3];
            *(uint4*)&vtb[(size_t)(chunk * 1024 + kc + vrow) * 1024 + vseg * 8] = o4;
        }

        // Gram MFMA: S[d][e] += sum_t K[d,t]*Q[e,t] over this 64-token slice
#pragma unroll
        for (int kk = 0; kk < 64; kk += 32) {
            bf16x8 af0 = *(const bf16x8*)&Ks[wm * 32 + l16][kk + qd * 8];
            bf16x8 af1 = *(const bf16x8*)&Ks[wm * 32 + 16 + l16][kk + qd * 8];
            bf16x8 bf0 = *(const bf16x8*)&Qs[wn4 * 16 + l16][kk + qd * 8];
            acc[0] = __builtin_amdgcn_mfma_f32_16x16x32_bf16(af0, bf0, acc[0], 0, 0, 0);
            acc[1] = __builtin_amdgcn_mfma_f32_16x16x32_bf16(af1, bf0, acc[1], 0, 0, 0);
        }

        // my LDS reads (and tap commits) done, then barrier (B2)
        asm volatile("s_waitcnt lgkmcnt(0)" ::: "memory");
        __builtin_amdgcn_s_barrier();
    }

    // S split-K accumulate (16 chunk-blocks per bh) — round-3 proven atomics path
    float* Sb = S + (size_t)(b * 16 + h) * 4096;
#pragma unroll
    for (int i = 0; i < 2; i++)
#pragma unroll
        for (int r = 0; r < 4; r++) {
            int d = wm * 32 + i * 16 + qd * 4 + r;
            int e = wn4 * 16 + l16;
            atomicAdd(&Sb[(size_t)d * 64 + e], acc[i][r]);
        }

    // norm partials: reduce over the 16 tq-lanes of each (pc) group
#pragma unroll
    for (int s = 0; s < 4; s++) {
        float v = ssl[s];
#pragma unroll
        for (int o = 1; o < 16; o <<= 1) v += __shfl_xor(v, o, 64);
        ssl[s] = v;
    }
    if ((lane & 15) == 0) {
        float* dst = (ts ? ssk : ssq) + b * INNER + chbase;
        atomicAdd(&dst[0], ssl[0]);
        atomicAdd(&dst[1], ssl[1]);
        atomicAdd(&dst[2], ssl[2]);
        atomicAdd(&dst[3], ssl[3]);
    }
}

// ---------------- K3: fold norms+rescale, softmax, write bf16 attn IN PLACE over S ----------------
__global__ __launch_bounds__(64) void k3_softmax(float* __restrict__ S,
                                                 const float* __restrict__ ssq,
                                                 const float* __restrict__ ssk,
                                                 const float* __restrict__ rescale) {
    int bh = blockIdx.x;  // 0..31
    int b = bh >> 4, h = bh & 15;
    int d = threadIdx.x;
    __shared__ float rq[64];
    int cbase = b * INNER + h * 64;
    rq[d] = 1.0f / fmaxf(sqrtf(ssq[cbase + d]), 1e-12f);
    float rk = 1.0f / fmaxf(sqrtf(ssk[cbase + d]), 1e-12f);
    __syncthreads();
    float rsc = rescale[h];
    const float* row = S + (size_t)bh * 4096 + (size_t)d * 64;
    float sv[64];
    float mx = -3.4e38f;
#pragma unroll
    for (int e = 0; e < 64; e++) {
        sv[e] = row[e] * rk * rq[e] * rsc;
        mx = fmaxf(mx, sv[e]);
    }
    float sum = 0.f;
#pragma unroll
    for (int e = 0; e < 64; e++) {
        sv[e] = expf(sv[e] - mx);
        sum += sv[e];
    }
    float inv = 1.0f / sum;
    __syncthreads();  // all reads of S[bh] complete before bf16 overwrite
    ushort* attn = (ushort*)((char*)S + (size_t)bh * 16384);
#pragma unroll
    for (int e = 0; e < 64; e++) attn[d * 64 + e] = f2bf(sv[e] * inv);
}

// ---------------- CVT: proj_w f32 -> bf16 ----------------
__global__ __launch_bounds__(256) void cvt_w(const float* __restrict__ w,
                                             bf16_t* __restrict__ wbf) {
    int i = (blockIdx.x * 256 + threadIdx.x) * 4;
    float4 f = *(const float4*)&w[i];
    ushort4 r;
    r.x = f2bf(f.x); r.y = f2bf(f.y); r.z = f2bf(f.z); r.w = f2bf(f.w);
    *(ushort4*)&wbf[i] = r;
}

// ---------------- K4 (MFMA): xo[d][t] = sum_e attn[d][e] * vt[t][h*64+e] ----------------
__global__ __launch_bounds__(256) void k4_mfma(const float* __restrict__ Sbase,
                                               const bf16_t* __restrict__ vt,
                                               bf16_t* __restrict__ xo) {
    int tt = blockIdx.x;  // 0..127 (128-token tiles)
    int h = blockIdx.y;   // 0..15
    int b = blockIdx.z;
    int bh = b * 16 + h;
    const ushort* attn = (const ushort*)((const char*)Sbase + (size_t)bh * 16384);
    __shared__ ushort As[64][72];
    __shared__ ushort Bs[128][72];
    int tid = threadIdx.x, lane = tid & 63, wave = tid >> 6;
    int wm = wave & 1, wn = wave >> 1;
    int qd = lane >> 4, l16 = lane & 15;
    int r0 = tid >> 3, c0 = (tid & 7) * 8;
#pragma unroll
    for (int l = 0; l < 2; l++) {
        int row = r0 + l * 32;
        *(uint4*)&As[row][c0] = *(const uint4*)&attn[row * 64 + c0];
    }
    const bf16_t* vtb = vt + (size_t)b * 16777216 + (size_t)(tt * 128) * 1024 + h * 64;
#pragma unroll
    for (int l = 0; l < 4; l++) {
        int row = r0 + l * 32;
        *(uint4*)&Bs[row][c0] = *(const uint4*)&vtb[(size_t)row * 1024 + c0];
    }
    __syncthreads();
    f32x4 acc[2][4];
#pragma unroll
    for (int i = 0; i < 2; i++)
#pragma unroll
        for (int j = 0; j < 4; j++) acc[i][j] = (f32x4){0.f, 0.f, 0.f, 0.f};
#pragma unroll
    for (int kk = 0; kk < 64; kk += 32) {
        bf16x8 af[2], bfr[4];
#pragma unroll
        for (int i = 0; i < 2; i++)
            af[i] = *(const bf16x8*)&As[wm * 32 + i * 16 + l16][kk + qd * 8];
#pragma unroll
        for (int j = 0; j < 4; j++)
            bfr[j] = *(const bf16x8*)&Bs[wn * 64 + j * 16 + l16][kk + qd * 8];
#pragma unroll
        for (int i = 0; i < 2; i++)
#pragma unroll
            for (int j = 0; j < 4; j++)
                acc[i][j] = __builtin_amdgcn_mfma_f32_16x16x32_bf16(af[i], bfr[j], acc[i][j], 0, 0, 0);
    }
    bf16_t* xob = xo + (size_t)b * 16777216 + (size_t)(h * 64) * NTOK + (size_t)tt * 128;
#pragma unroll
    for (int i = 0; i < 2; i++)
#pragma unroll
        for (int j = 0; j < 4; j++)
#pragma unroll
            for (int r = 0; r < 4; r++) {
                int d = wm * 32 + i * 16 + qd * 4 + r;
                int t = wn * 64 + j * 16 + l16;
                xob[(size_t)d * NTOK + t] = f2bf(acc[i][j][r]);
            }
}

// ---------------- GEMM-TN (MFMA): C[m][n] = sum_k A[m][k]*B[n][k] + bias ----------------
// FUSE_PE2=0: C bf16, += bias (bias_on_n selects axis).
// FUSE_PE2=1: C f32 = acc + bias[n] + pe2[n_global][m_global] (transposed add; k9 fused away).
template <int FUSE_PE2>
__global__ __launch_bounds__(256) void gemm_tn(
    const bf16_t* __restrict__ A, const bf16_t* __restrict__ B,
    const float* __restrict__ pb, void* __restrict__ Cv,
    int lda, int ldb, int ldc, int K,
    long strideA, long strideB, long strideC, int bias_on_n,
    const bf16_t* __restrict__ pe2) {
    int mb = blockIdx.x, nb = blockIdx.y, b = blockIdx.z;
    A += (size_t)b * strideA;
    B += (size_t)b * strideB;
    __shared__ ushort smem[2 * 128 * 72];
    ushort (*As)[72] = (ushort(*)[72])smem;
    ushort (*Bs)[72] = (ushort(*)[72])(smem + 128 * 72);
    int tid = threadIdx.x;
    int lane = tid & 63, wave = tid >> 6;
    int wm = wave & 1, wn = wave >> 1;
    int q = lane >> 4, l16 = lane & 15;
    f32x4 acc[4][4];
#pragma unroll
    for (int i = 0; i < 4; i++)
#pragma unroll
        for (int j = 0; j < 4; j++) acc[i][j] = (f32x4){0.f, 0.f, 0.f, 0.f};
    const bf16_t* Ab = A + (size_t)mb * 128 * lda;
    const bf16_t* Bb = B + (size_t)nb * 128 * ldb;
    int r0 = tid >> 3;
    int c0 = (tid & 7) * 8;
#pragma unroll 1
    for (int kc = 0; kc < K; kc += 64) {
#pragma unroll
        for (int l = 0; l < 4; l++) {
            int row = l * 32 + r0;
            *(uint4*)&As[row][c0] = *(const uint4*)&Ab[(size_t)row * lda + kc + c0];
            *(uint4*)&Bs[row][c0] = *(const uint4*)&Bb[(size_t)row * ldb + kc + c0];
        }
        __syncthreads();
#pragma unroll
        for (int kk = 0; kk < 64; kk += 32) {
            bf16x8 af[4], bfr[4];
#pragma unroll
            for (int i = 0; i < 4; i++)
                af[i] = *(const bf16x8*)&As[wm * 64 + i * 16 + l16][kk + q * 8];
#pragma unroll
            for (int j = 0; j < 4; j++)
                bfr[j] = *(const bf16x8*)&Bs[wn * 64 + j * 16 + l16][kk + q * 8];
#pragma unroll
            for (int i = 0; i < 4; i++)
#pragma unroll
                for (int j = 0; j < 4; j++)
                    acc[i][j] = __builtin_amdgcn_mfma_f32_16x16x32_bf16(af[i], bfr[j], acc[i][j], 0, 0, 0);
        }
        __syncthreads();
    }
    if (FUSE_PE2) {
        // stage pe2 tile [128 n][128 m] (bf16, stride 132) into reused smem
        const bf16_t* peb = pe2 + (size_t)b * 4194304;
        int gm0 = mb * 128, gn0 = nb * 128;
        for (int u = tid; u < 128 * 16; u += 256) {
            int row = u >> 4, seg = u & 15;
            *(uint4*)&smem[row * 132 + seg * 8] =
                *(const uint4*)&peb[(size_t)(gn0 + row) * NTOK + gm0 + seg * 8];
        }
        __syncthreads();
        float* C = (float*)Cv + (size_t)b * strideC;
#pragma unroll
        for (int i = 0; i < 4; i++) {
#pragma unroll
            for (int j = 0; j < 4; j++) {
                int n = wn * 64 + j * 16 + l16;
                int gn = gn0 + n;
                int m0 = wm * 64 + i * 16 + q * 4;
                ushort4 pv4 = *(const ushort4*)&smem[n * 132 + m0];
                float bias = pb[gn];
#pragma unroll
                for (int r = 0; r < 4; r++) {
                    ushort pu = (r == 0) ? pv4.x : ((r == 1) ? pv4.y : ((r == 2) ? pv4.z : pv4.w));
                    C[(size_t)(gm0 + m0 + r) * ldc + gn] = acc[i][j][r] + bias + bf2f(pu);
                }
            }
        }
    } else {
        bf16_t* C = (bf16_t*)Cv + (size_t)b * strideC;
#pragma unroll
        for (int i = 0; i < 4; i++) {
#pragma unroll
            for (int j = 0; j < 4; j++) {
                int n = wn * 64 + j * 16 + l16;
                int gn = nb * 128 + n;
#pragma unroll
                for (int r = 0; r < 4; r++) {
                    int m = wm * 64 + i * 16 + q * 4 + r;
                    int gm = mb * 128 + m;
                    float bias = bias_on_n ? pb[gn] : pb[gm];
                    C[(size_t)gm * ldc + gn] = f2bf(acc[i][j][r] + bias);
                }
            }
        }
    }
}

// ---------------- K78: fused depthwise 3x3 (GELU) -> depthwise 3x3, pe1 stays in LDS ----------------
__global__ __launch_bounds__(256) void k_pos_fused(const bf16_t* __restrict__ vp,
                                                   const float* __restrict__ w1t,
                                                   const float* __restrict__ w2t,
                                                   bf16_t* __restrict__ pe2) {
    int ychunk = blockIdx.x;  // 0..15
    int ch = blockIdx.y;      // 0..255
    int b = blockIdx.z;
    int y0 = ychunk * 8;
    __shared__ float t1[12][132];
    __shared__ float t2[10][132];
    const bf16_t* plane = vp + (size_t)b * 4194304 + (size_t)ch * NTOK;
    for (int idx = threadIdx.x; idx < 12 * 132; idx += 256) {
        int i = idx / 132, c = idx % 132;
        int gy = y0 - 2 + i, gx = c - 2;
        float val = 0.f;
        if (gy >= 0 && gy < HH && gx >= 0 && gx < WW) val = bf2f(plane[gy * WW + gx]);
        t1[i][c] = val;
    }
    float wa[9], wb[9];
#pragma unroll
    for (int t = 0; t < 9; t++) {
        wa[t] = w1t[(size_t)ch * 9 + t];
        wb[t] = w2t[(size_t)ch * 9 + t];
    }
    __syncthreads();
    // pe1 rows i=0..9 (y=y0-1+i), cols c1=0..129 (x=c1-1); zero outside image (2nd conv zero-pads pe1)
    for (int idx = threadIdx.x; idx < 10 * 130; idx += 256) {
        int i = idx / 130, c1 = idx % 130;
        int yy = y0 - 1 + i, xx = c1 - 1;
        float val = 0.f;
        if (yy >= 0 && yy < HH && xx >= 0 && xx < WW) {
            float a = wa[0] * t1[i][c1]     + wa[1] * t1[i][c1 + 1]     + wa[2] * t1[i][c1 + 2]
                    + wa[3] * t1[i + 1][c1] + wa[4] * t1[i + 1][c1 + 1] + wa[5] * t1[i + 1][c1 + 2]
                    + wa[6] * t1[i + 2][c1] + wa[7] * t1[i + 2][c1 + 1] + wa[8] * t1[i + 2][c1 + 2];
            val = 0.5f * a * (1.0f + erff(a * 0.70710678118654752f));
        }
        t2[i][c1] = val;
    }
    __syncthreads();
    int x = threadIdx.x & 127;
    int half = threadIdx.x >> 7;
    bf16_t* oplane = pe2 + (size_t)b * 4194304 + (size_t)ch * NTOK;
#pragma unroll
    for (int rp = 0; rp < 4; rp++) {
        int r = rp * 2 + half;
        float acc = wb[0] * t2[r][x]     + wb[1] * t2[r][x + 1]     + wb[2] * t2[r][x + 2]
                  + wb[3] * t2[r + 1][x] + wb[4] * t2[r + 1][x + 1] + wb[5] * t2[r + 1][x + 2]
                  + wb[6] * t2[r + 2][x] + wb[7] * t2[r + 2][x + 1] + wb[8] * t2[r + 2][x + 2];
        oplane[(size_t)(y0 + r) * WW + x] = f2bf(acc);
    }
}

extern "C" void kernel_launch(void* const* d_in, const int* in_sizes, int n_in,
                              void* d_out, int out_size, void* d_ws, size_t ws_size,
                              hipStream_t stream) {
    const float* x_in    = (const float*)d_in[0];
    const float* wq      = (const float*)d_in[1];
    const float* wk      = (const float*)d_in[2];
    const float* wv      = (const float*)d_in[3];
    const float* qg      = (const float*)d_in[4];
    const float* qb      = (const float*)d_in[5];
    const float* qm      = (const float*)d_in[6];
    const float* qv      = (const float*)d_in[7];
    const float* kg      = (const float*)d_in[8];
    const float* kb      = (const float*)d_in[9];
    const float* km      = (const float*)d_in[10];
    const float* kv_     = (const float*)d_in[11];
    const float* vg      = (const float*)d_in[12];
    const float* vb      = (const float*)d_in[13];
    const float* vm      = (const float*)d_in[14];
    const float* vv      = (const float*)d_in[15];
    const float* rescale = (const float*)d_in[16];
    const float* proj_w  = (const float*)d_in[17];
    const float* proj_b  = (const float*)d_in[18];
    const float* pos_w1  = (const float*)d_in[19];
    const float* pos_w2  = (const float*)d_in[20];

    char* ws = (char*)d_ws;
    bf16_t* vt   = (bf16_t*)(ws + OFF_VT);
    bf16_t* xo   = (bf16_t*)(ws + OFF_XO);
    bf16_t* vp   = (bf16_t*)(ws + OFF_VP);
    bf16_t* pe2  = (bf16_t*)(ws + OFF_PE2);
    bf16_t* wbf  = (bf16_t*)(ws + OFF_WBF);
    float* S     = (float*)(ws + OFF_S);
    float* ssq   = (float*)(ws + OFF_SSQ);
    float* ssk   = (float*)(ws + OFF_SSK);

    hipMemsetAsync(ws + OFF_S, 0, (size_t)540672, stream);

    k12_fused<<<dim3(16, 16, 2), 512, 0, stream>>>(x_in, wq, wk, wv,
                                                   qg, qb, qm, qv,
                                                   kg, kb, km, kv_,
                                                   vg, vb, vm, vv,
                                                   vt, S, ssq, ssk);
    k3_softmax<<<dim3(32), 64, 0, stream>>>(S, ssq, ssk, rescale);
    cvt_w<<<dim3(256), 256, 0, stream>>>(proj_w, wbf);
    k4_mfma<<<dim3(128, 16, 2), 256, 0, stream>>>(S, vt, xo);
    // k6: vp[co][t] = W[co][:] . vt[t][:]          (M=256,N=16384,K=1024)
    gemm_tn<0><<<dim3(2, 128, 2), 256, 0, stream>>>(wbf, vt, proj_b, vp,
                                                    1024, 1024, 16384, 1024,
                                                    0L, 16777216L, 4194304L, 0, nullptr);
    k_pos_fused<<<dim3(16, 256, 2), 256, 0, stream>>>(vp, pos_w1, pos_w2, pe2);
    // k5': out[t][co] = xo_flat[t][:] . W[co][:] + bias + pe2[co][t]  (f32, k9 fused)
    gemm_tn<1><<<dim3(128, 2, 2), 256, 0, stream>>>(xo, wbf, proj_b, d_out,
                                                    1024, 1024, 256, 1024,
                                                    16777216L, 0L, 4194304L, 1, pe2);
}

// Round 8
// 311.777 us; speedup vs baseline: 1.1705x; 1.1705x over previous
//
#include <hip/hip_runtime.h>

#define NTOK 16384
#define CDIM 256
#define INNER 1024
#define WW 128
#define HH 128

typedef unsigned short bf16_t;
typedef __bf16 bf16x8 __attribute__((ext_vector_type(8)));
typedef float f32x4 __attribute__((ext_vector_type(4)));

__device__ __forceinline__ float bf2f(bf16_t u) {
    union { unsigned int i; float f; } x;
    x.i = ((unsigned int)u) << 16;
    return x.f;
}
__device__ __forceinline__ bf16_t f2bf(float f) {
    union { float f; unsigned int i; } x;
    x.f = f;
    unsigned int r = x.i + 0x7FFFu + ((x.i >> 16) & 1u);
    return (bf16_t)(r >> 16);
}
// pack two f32 -> u32 of 2 bf16 (RNE), T12 recipe (no builtin on gfx950)
__device__ __forceinline__ unsigned int cvtpk(float a, float b) {
    unsigned int r;
    asm("v_cvt_pk_bf16_f32 %0, %1, %2" : "=v"(r) : "v"(a), "v"(b));
    return r;
}

// workspace byte offsets (round-3 layout; xn/outc regions unused)
static const size_t OFF_VT   = 16777216;   // bf16 [2][16384][1024] (written directly by k12)
static const size_t OFF_XO   = 83886080;   // bf16 [2][1024][16384]
static const size_t OFF_VP   = 150994944;
static const size_t OFF_PE2  = 184549376;
static const size_t OFF_WBF  = 201326592;
static const size_t OFF_S    = 218103808;  // f32 [2][16][64][64]; attn bf16 in-place after k3
static const size_t OFF_SSQ  = 218628096;
static const size_t OFF_SSK  = 218636288;

// ---------------- K12: fused conv3x3+BN (q,k,v) + Gram MFMA + direct vt emit ----------------
// v8 = EXACT round-3 revert (proven 104 us). Post-mortems: occupancy (r4/r5), barrier vmcnt
// drain (r6), and intra-block staging pipeline (r7: FETCH 99->355 MB — the synchronized
// staging burst is what makes h-adjacent blocks share 128B L2 lines; spreading fetches
// over the kernel destroys that) are ALL refuted as levers. k12 is at its structural floor.
__global__ __launch_bounds__(512, 4) void k12_fused(
    const float* __restrict__ x,
    const float* __restrict__ wq, const float* __restrict__ wk, const float* __restrict__ wv,
    const float* __restrict__ qg, const float* __restrict__ qb, const float* __restrict__ qm, const float* __restrict__ qv,
    const float* __restrict__ kg, const float* __restrict__ kb, const float* __restrict__ km, const float* __restrict__ kv_,
    const float* __restrict__ vg, const float* __restrict__ vb, const float* __restrict__ vm, const float* __restrict__ vv,
    bf16_t* __restrict__ vt, float* __restrict__ S,
    float* __restrict__ ssq, float* __restrict__ ssk) {
    int chunk = blockIdx.x;   // 0..15 (8 image rows each)
    int h = blockIdx.y;       // 0..15
    int b = blockIdx.z;
    int y0 = chunk * 8;

    __shared__ ushort taps[16][10][132];      // 42,240 B (plane pp, gy=y0-1+i, gx=c-1)
    __shared__ ushort Qs[64][72];             // 9,216 B  [ch][t_local]
    __shared__ ushort Ks[64][72];             // 9,216 B
    __shared__ unsigned int Vs32[64][34];     // 8,704 B  [t_local][ch-pair]

    int tid = threadIdx.x;
    int lane = tid & 63, wave = tid >> 6;

    // ---- stage taps from x f32: 1300 positions x 4 ch-quads (16B each) ----
    {
        const float* xb = x + (size_t)b * NTOK * CDIM + h * 16;
        for (int u = tid; u < 5200; u += 512) {
            int pos = u >> 2, quad = u & 3;
            int i = pos / 130, c = pos - i * 130;
            int gy = y0 - 1 + i, gx = c - 1;
            if (gy >= 0 && gy < HH && gx >= 0 && gx < WW) {
                float4 v = *(const float4*)&xb[(size_t)(gy * WW + gx) * CDIM + quad * 4];
                taps[quad * 4 + 0][i][c] = f2bf(v.x);
                taps[quad * 4 + 1][i][c] = f2bf(v.y);
                taps[quad * 4 + 2][i][c] = f2bf(v.z);
                taps[quad * 4 + 3][i][c] = f2bf(v.w);
            } else {
                taps[quad * 4 + 0][i][c] = 0;
                taps[quad * 4 + 1][i][c] = 0;
                taps[quad * 4 + 2][i][c] = 0;
                taps[quad * 4 + 3][i][c] = 0;
            }
        }
    }

    // ---- per-thread roles ----
    int tq = tid & 15;          // token quad: 4 tokens x0..x0+3
    int pc = (tid >> 4) & 15;   // input plane (0..15) -> 4 output channels
    int ts = tid >> 8;          // 0: q-tensor, 1: k-tensor (wave-uniform)

    // ---- preload folded weights: q-or-k (4 ch) and v half (2 ch) ----
    const float* wsrc = ts ? wk : wq;
    const float* gp = ts ? kg : qg;
    const float* bp = ts ? kb : qb;
    const float* mp = ts ? km : qm;
    const float* vp_ = ts ? kv_ : qv;
    int chbase = h * 64 + pc * 4;
    float wQK[4][9], shQK[4];
#pragma unroll
    for (int s = 0; s < 4; s++) {
        int ch = chbase + s;
        float sc = gp[ch] * rsqrtf(vp_[ch] + 1e-5f);
        shQK[s] = bp[ch] - mp[ch] * sc;
#pragma unroll
        for (int t = 0; t < 9; t++) wQK[s][t] = wsrc[(size_t)ch * 9 + t] * sc;
    }
    float wV[2][9], shV[2];
#pragma unroll
    for (int sv = 0; sv < 2; sv++) {
        int ch = chbase + 2 * ts + sv;
        float sc = vg[ch] * rsqrtf(vv[ch] + 1e-5f);
        shV[sv] = vb[ch] - vm[ch] * sc;
#pragma unroll
        for (int t = 0; t < 9; t++) wV[sv][t] = wv[(size_t)ch * 9 + t] * sc;
    }

    ushort (*QK)[72] = ts ? Ks : Qs;

    // MFMA partition (proven k2 pattern, 8-wave split)
    int wm = wave & 1;          // d half (32)
    int wn4 = wave >> 1;        // e quarter (16)
    int qd = lane >> 4, l16 = lane & 15;
    f32x4 acc[2];
    acc[0] = (f32x4){0.f, 0.f, 0.f, 0.f};
    acc[1] = (f32x4){0.f, 0.f, 0.f, 0.f};

    // vt store role
    int vrow = tid >> 3;        // t_local 0..63
    int vseg = tid & 7;         // 8-ch segment
    bf16_t* vtb = vt + (size_t)b * 16777216 + (size_t)h * 64;

    float ssl[4] = {0.f, 0.f, 0.f, 0.f};

    __syncthreads();

#pragma unroll 1
    for (int kc = 0; kc < 1024; kc += 64) {
        int grp = kc >> 6;
        int ly = grp >> 1;              // local output row 0..7
        int xh = (grp & 1) << 6;        // 0 or 64
        int x0 = xh + tq * 4;

        // tap window rows ly..ly+2, cols x0..x0+5 of plane pc
        float tp[3][6];
#pragma unroll
        for (int i = 0; i < 3; i++) {
            const ushort* rp = &taps[pc][ly + i][x0];
            ushort4 u4 = *(const ushort4*)rp;
            ushort2 u2 = *(const ushort2*)(rp + 4);
            tp[i][0] = bf2f(u4.x); tp[i][1] = bf2f(u4.y);
            tp[i][2] = bf2f(u4.z); tp[i][3] = bf2f(u4.w);
            tp[i][4] = bf2f(u2.x); tp[i][5] = bf2f(u2.y);
        }

        // q-or-k: 4 channels x 4 tokens
#pragma unroll
        for (int s = 0; s < 4; s++) {
            float o0 = shQK[s], o1 = shQK[s], o2 = shQK[s], o3 = shQK[s];
#pragma unroll
            for (int i = 0; i < 3; i++) {
                float wa = wQK[s][i * 3 + 0], wb = wQK[s][i * 3 + 1], wc = wQK[s][i * 3 + 2];
                o0 += wa * tp[i][0] + wb * tp[i][1] + wc * tp[i][2];
                o1 += wa * tp[i][1] + wb * tp[i][2] + wc * tp[i][3];
                o2 += wa * tp[i][2] + wb * tp[i][3] + wc * tp[i][4];
                o3 += wa * tp[i][3] + wb * tp[i][4] + wc * tp[i][5];
            }
            ssl[s] += o0 * o0 + o1 * o1 + o2 * o2 + o3 * o3;
            uint2 pk;
            pk.x = cvtpk(o0, o1);
            pk.y = cvtpk(o2, o3);
            *(uint2*)&QK[pc * 4 + s][tq * 4] = pk;
        }

        // v: 2 channels (pair pc*2+ts) x 4 tokens
        {
            float ov[2][4];
#pragma unroll
            for (int sv = 0; sv < 2; sv++) {
                float o0 = shV[sv], o1 = shV[sv], o2 = shV[sv], o3 = shV[sv];
#pragma unroll
                for (int i = 0; i < 3; i++) {
                    float wa = wV[sv][i * 3 + 0], wb = wV[sv][i * 3 + 1], wc = wV[sv][i * 3 + 2];
                    o0 += wa * tp[i][0] + wb * tp[i][1] + wc * tp[i][2];
                    o1 += wa * tp[i][1] + wb * tp[i][2] + wc * tp[i][3];
                    o2 += wa * tp[i][2] + wb * tp[i][3] + wc * tp[i][4];
                    o3 += wa * tp[i][3] + wb * tp[i][4] + wc * tp[i][5];
                }
                ov[sv][0] = o0; ov[sv][1] = o1; ov[sv][2] = o2; ov[sv][3] = o3;
            }
#pragma unroll
            for (int j = 0; j < 4; j++)
                Vs32[tq * 4 + j][pc * 2 + ts] = cvtpk(ov[0][j], ov[1][j]);
        }

        __syncthreads();

        // vt emit: row t_local -> [t][64ch] slab, coalesced 128B segments
        {
            uint4 o4;
            o4.x = Vs32[vrow][vseg * 4 + 0];
            o4.y = Vs32[vrow][vseg * 4 + 1];
            o4.z = Vs32[vrow][vseg * 4 + 2];
            o4.w = Vs32[vrow][vseg * 4 + 3];
            *(uint4*)&vtb[(size_t)(chunk * 1024 + kc + vrow) * 1024 + vseg * 8] = o4;
        }

        // Gram MFMA: S[d][e] += sum_t K[d,t]*Q[e,t] over this 64-token slice
#pragma unroll
        for (int kk = 0; kk < 64; kk += 32) {
            bf16x8 af0 = *(const bf16x8*)&Ks[wm * 32 + l16][kk + qd * 8];
            bf16x8 af1 = *(const bf16x8*)&Ks[wm * 32 + 16 + l16][kk + qd * 8];
            bf16x8 bf0 = *(const bf16x8*)&Qs[wn4 * 16 + l16][kk + qd * 8];
            acc[0] = __builtin_amdgcn_mfma_f32_16x16x32_bf16(af0, bf0, acc[0], 0, 0, 0);
            acc[1] = __builtin_amdgcn_mfma_f32_16x16x32_bf16(af1, bf0, acc[1], 0, 0, 0);
        }

        __syncthreads();
    }

    // S split-K accumulate (16 chunk-blocks per bh)
    float* Sb = S + (size_t)(b * 16 + h) * 4096;
#pragma unroll
    for (int i = 0; i < 2; i++)
#pragma unroll
        for (int r = 0; r < 4; r++) {
            int d = wm * 32 + i * 16 + qd * 4 + r;
            int e = wn4 * 16 + l16;
            atomicAdd(&Sb[(size_t)d * 64 + e], acc[i][r]);
        }

    // norm partials: reduce over the 16 tq-lanes of each (pc) group
#pragma unroll
    for (int s = 0; s < 4; s++) {
        float v = ssl[s];
#pragma unroll
        for (int o = 1; o < 16; o <<= 1) v += __shfl_xor(v, o, 64);
        ssl[s] = v;
    }
    if ((lane & 15) == 0) {
        float* dst = (ts ? ssk : ssq) + b * INNER + chbase;
        atomicAdd(&dst[0], ssl[0]);
        atomicAdd(&dst[1], ssl[1]);
        atomicAdd(&dst[2], ssl[2]);
        atomicAdd(&dst[3], ssl[3]);
    }
}

// ---------------- K3: fold norms+rescale, softmax, write bf16 attn IN PLACE over S ----------------
// v8: float4 row loads (was 4B scalar at 256B lane stride — worst-case coalescing).
__global__ __launch_bounds__(64) void k3_softmax(float* __restrict__ S,
                                                 const float* __restrict__ ssq,
                                                 const float* __restrict__ ssk,
                                                 const float* __restrict__ rescale) {
    int bh = blockIdx.x;  // 0..31
    int b = bh >> 4, h = bh & 15;
    int d = threadIdx.x;
    __shared__ float rq[64];
    int cbase = b * INNER + h * 64;
    rq[d] = 1.0f / fmaxf(sqrtf(ssq[cbase + d]), 1e-12f);
    float rk = 1.0f / fmaxf(sqrtf(ssk[cbase + d]), 1e-12f);
    __syncthreads();
    float rsc = rescale[h];
    const float* row = S + (size_t)bh * 4096 + (size_t)d * 64;
    float sv[64];
#pragma unroll
    for (int e4 = 0; e4 < 16; e4++) {
        float4 v4 = *(const float4*)&row[e4 * 4];
        sv[e4 * 4 + 0] = v4.x;
        sv[e4 * 4 + 1] = v4.y;
        sv[e4 * 4 + 2] = v4.z;
        sv[e4 * 4 + 3] = v4.w;
    }
    float mx = -3.4e38f;
#pragma unroll
    for (int e = 0; e < 64; e++) {
        sv[e] = sv[e] * rk * rq[e] * rsc;
        mx = fmaxf(mx, sv[e]);
    }
    float sum = 0.f;
#pragma unroll
    for (int e = 0; e < 64; e++) {
        sv[e] = expf(sv[e] - mx);
        sum += sv[e];
    }
    float inv = 1.0f / sum;
    __syncthreads();  // all reads of S[bh] complete before bf16 overwrite
    ushort* attn = (ushort*)((char*)S + (size_t)bh * 16384);
#pragma unroll
    for (int e = 0; e < 64; e++) attn[d * 64 + e] = f2bf(sv[e] * inv);
}

// ---------------- CVT: proj_w f32 -> bf16 ----------------
__global__ __launch_bounds__(256) void cvt_w(const float* __restrict__ w,
                                             bf16_t* __restrict__ wbf) {
    int i = (blockIdx.x * 256 + threadIdx.x) * 4;
    float4 f = *(const float4*)&w[i];
    ushort4 r;
    r.x = f2bf(f.x); r.y = f2bf(f.y); r.z = f2bf(f.z); r.w = f2bf(f.w);
    *(ushort4*)&wbf[i] = r;
}

// ---------------- K4 (MFMA): xo[d][t] = sum_e attn[d][e] * vt[t][h*64+e] ----------------
__global__ __launch_bounds__(256) void k4_mfma(const float* __restrict__ Sbase,
                                               const bf16_t* __restrict__ vt,
                                               bf16_t* __restrict__ xo) {
    int tt = blockIdx.x;  // 0..127 (128-token tiles)
    int h = blockIdx.y;   // 0..15
    int b = blockIdx.z;
    int bh = b * 16 + h;
    const ushort* attn = (const ushort*)((const char*)Sbase + (size_t)bh * 16384);
    __shared__ ushort As[64][72];
    __shared__ ushort Bs[128][72];
    int tid = threadIdx.x, lane = tid & 63, wave = tid >> 6;
    int wm = wave & 1, wn = wave >> 1;
    int qd = lane >> 4, l16 = lane & 15;
    int r0 = tid >> 3, c0 = (tid & 7) * 8;
#pragma unroll
    for (int l = 0; l < 2; l++) {
        int row = r0 + l * 32;
        *(uint4*)&As[row][c0] = *(const uint4*)&attn[row * 64 + c0];
    }
    const bf16_t* vtb = vt + (size_t)b * 16777216 + (size_t)(tt * 128) * 1024 + h * 64;
#pragma unroll
    for (int l = 0; l < 4; l++) {
        int row = r0 + l * 32;
        *(uint4*)&Bs[row][c0] = *(const uint4*)&vtb[(size_t)row * 1024 + c0];
    }
    __syncthreads();
    f32x4 acc[2][4];
#pragma unroll
    for (int i = 0; i < 2; i++)
#pragma unroll
        for (int j = 0; j < 4; j++) acc[i][j] = (f32x4){0.f, 0.f, 0.f, 0.f};
#pragma unroll
    for (int kk = 0; kk < 64; kk += 32) {
        bf16x8 af[2], bfr[4];
#pragma unroll
        for (int i = 0; i < 2; i++)
            af[i] = *(const bf16x8*)&As[wm * 32 + i * 16 + l16][kk + qd * 8];
#pragma unroll
        for (int j = 0; j < 4; j++)
            bfr[j] = *(const bf16x8*)&Bs[wn * 64 + j * 16 + l16][kk + qd * 8];
#pragma unroll
        for (int i = 0; i < 2; i++)
#pragma unroll
            for (int j = 0; j < 4; j++)
                acc[i][j] = __builtin_amdgcn_mfma_f32_16x16x32_bf16(af[i], bfr[j], acc[i][j], 0, 0, 0);
    }
    bf16_t* xob = xo + (size_t)b * 16777216 + (size_t)(h * 64) * NTOK + (size_t)tt * 128;
#pragma unroll
    for (int i = 0; i < 2; i++)
#pragma unroll
        for (int j = 0; j < 4; j++)
#pragma unroll
            for (int r = 0; r < 4; r++) {
                int d = wm * 32 + i * 16 + qd * 4 + r;
                int t = wn * 64 + j * 16 + l16;
                xob[(size_t)d * NTOK + t] = f2bf(acc[i][j][r]);
            }
}

// ---------------- GEMM-TN (MFMA): C[m][n] = sum_k A[m][k]*B[n][k] + bias ----------------
// FUSE_PE2=0: C bf16, += bias (bias_on_n selects axis).
// FUSE_PE2=1: C f32 = acc + bias[n] + pe2[n_global][m_global] (transposed add; k9 fused away).
template <int FUSE_PE2>
__global__ __launch_bounds__(256) void gemm_tn(
    const bf16_t* __restrict__ A, const bf16_t* __restrict__ B,
    const float* __restrict__ pb, void* __restrict__ Cv,
    int lda, int ldb, int ldc, int K,
    long strideA, long strideB, long strideC, int bias_on_n,
    const bf16_t* __restrict__ pe2) {
    int mb = blockIdx.x, nb = blockIdx.y, b = blockIdx.z;
    A += (size_t)b * strideA;
    B += (size_t)b * strideB;
    __shared__ ushort smem[2 * 128 * 72];
    ushort (*As)[72] = (ushort(*)[72])smem;
    ushort (*Bs)[72] = (ushort(*)[72])(smem + 128 * 72);
    int tid = threadIdx.x;
    int lane = tid & 63, wave = tid >> 6;
    int wm = wave & 1, wn = wave >> 1;
    int q = lane >> 4, l16 = lane & 15;
    f32x4 acc[4][4];
#pragma unroll
    for (int i = 0; i < 4; i++)
#pragma unroll
        for (int j = 0; j < 4; j++) acc[i][j] = (f32x4){0.f, 0.f, 0.f, 0.f};
    const bf16_t* Ab = A + (size_t)mb * 128 * lda;
    const bf16_t* Bb = B + (size_t)nb * 128 * ldb;
    int r0 = tid >> 3;
    int c0 = (tid & 7) * 8;
#pragma unroll 1
    for (int kc = 0; kc < K; kc += 64) {
#pragma unroll
        for (int l = 0; l < 4; l++) {
            int row = l * 32 + r0;
            *(uint4*)&As[row][c0] = *(const uint4*)&Ab[(size_t)row * lda + kc + c0];
            *(uint4*)&Bs[row][c0] = *(const uint4*)&Bb[(size_t)row * ldb + kc + c0];
        }
        __syncthreads();
#pragma unroll
        for (int kk = 0; kk < 64; kk += 32) {
            bf16x8 af[4], bfr[4];
#pragma unroll
            for (int i = 0; i < 4; i++)
                af[i] = *(const bf16x8*)&As[wm * 64 + i * 16 + l16][kk + q * 8];
#pragma unroll
            for (int j = 0; j < 4; j++)
                bfr[j] = *(const bf16x8*)&Bs[wn * 64 + j * 16 + l16][kk + q * 8];
#pragma unroll
            for (int i = 0; i < 4; i++)
#pragma unroll
                for (int j = 0; j < 4; j++)
                    acc[i][j] = __builtin_amdgcn_mfma_f32_16x16x32_bf16(af[i], bfr[j], acc[i][j], 0, 0, 0);
        }
        __syncthreads();
    }
    if (FUSE_PE2) {
        // stage pe2 tile [128 n][128 m] (bf16, stride 132) into reused smem
        const bf16_t* peb = pe2 + (size_t)b * 4194304;
        int gm0 = mb * 128, gn0 = nb * 128;
        for (int u = tid; u < 128 * 16; u += 256) {
            int row = u >> 4, seg = u & 15;
            *(uint4*)&smem[row * 132 + seg * 8] =
                *(const uint4*)&peb[(size_t)(gn0 + row) * NTOK + gm0 + seg * 8];
        }
        __syncthreads();
        float* C = (float*)Cv + (size_t)b * strideC;
#pragma unroll
        for (int i = 0; i < 4; i++) {
#pragma unroll
            for (int j = 0; j < 4; j++) {
                int n = wn * 64 + j * 16 + l16;
                int gn = gn0 + n;
                int m0 = wm * 64 + i * 16 + q * 4;
                ushort4 pv4 = *(const ushort4*)&smem[n * 132 + m0];
                float bias = pb[gn];
#pragma unroll
                for (int r = 0; r < 4; r++) {
                    ushort pu = (r == 0) ? pv4.x : ((r == 1) ? pv4.y : ((r == 2) ? pv4.z : pv4.w));
                    C[(size_t)(gm0 + m0 + r) * ldc + gn] = acc[i][j][r] + bias + bf2f(pu);
                }
            }
        }
    } else {
        bf16_t* C = (bf16_t*)Cv + (size_t)b * strideC;
#pragma unroll
        for (int i = 0; i < 4; i++) {
#pragma unroll
            for (int j = 0; j < 4; j++) {
                int n = wn * 64 + j * 16 + l16;
                int gn = nb * 128 + n;
#pragma unroll
                for (int r = 0; r < 4; r++) {
                    int m = wm * 64 + i * 16 + q * 4 + r;
                    int gm = mb * 128 + m;
                    float bias = bias_on_n ? pb[gn] : pb[gm];
                    C[(size_t)gm * ldc + gn] = f2bf(acc[i][j][r] + bias);
                }
            }
        }
    }
}

// ---------------- K78: fused depthwise 3x3 (GELU) -> depthwise 3x3, pe1 stays in LDS ----------------
// v8: vectorized t1 staging — interior cols load as uint4 (8 bf16, was scalar 2B loads:
// Common-mistake #2), edge cols zeroed separately. 1584 scalar loads -> 192 x 16B loads.
__global__ __launch_bounds__(256) void k_pos_fused(const bf16_t* __restrict__ vp,
                                                   const float* __restrict__ w1t,
                                                   const float* __restrict__ w2t,
                                                   bf16_t* __restrict__ pe2) {
    int ychunk = blockIdx.x;  // 0..15
    int ch = blockIdx.y;      // 0..255
    int b = blockIdx.z;
    int y0 = ychunk * 8;
    __shared__ float t1[12][132];
    __shared__ float t2[10][132];
    const bf16_t* plane = vp + (size_t)b * 4194304 + (size_t)ch * NTOK;
    // edge cols {0,1,130,131} x 12 rows -> always zero (gx=-2,-1,128,129 OOB)
    if (threadIdx.x < 48) {
        int i = threadIdx.x >> 2, e = threadIdx.x & 3;
        int c = (e < 2) ? e : (128 + e);
        t1[i][c] = 0.f;
    }
    // interior: rows i=0..11 (gy=y0-2+i), cols c=2..129 (gx=0..127) as 16 x uint4 per row
    for (int u = threadIdx.x; u < 192; u += 256) {
        int i = u >> 4, seg = u & 15;
        int gy = y0 - 2 + i;
        float v[8];
        if (gy >= 0 && gy < HH) {
            uint4 raw = *(const uint4*)&plane[gy * WW + seg * 8];
            unsigned int w0 = raw.x, w1 = raw.y, w2 = raw.z, w3 = raw.w;
            v[0] = bf2f((ushort)(w0 & 0xffffu)); v[1] = bf2f((ushort)(w0 >> 16));
            v[2] = bf2f((ushort)(w1 & 0xffffu)); v[3] = bf2f((ushort)(w1 >> 16));
            v[4] = bf2f((ushort)(w2 & 0xffffu)); v[5] = bf2f((ushort)(w2 >> 16));
            v[6] = bf2f((ushort)(w3 & 0xffffu)); v[7] = bf2f((ushort)(w3 >> 16));
        } else {
#pragma unroll
            for (int j = 0; j < 8; j++) v[j] = 0.f;
        }
        float* dst = &t1[i][2 + seg * 8];  // 8B-aligned (row base 16B-aligned + 8B)
#pragma unroll
        for (int j = 0; j < 4; j++) {
            float2 p; p.x = v[2 * j]; p.y = v[2 * j + 1];
            *(float2*)&dst[2 * j] = p;
        }
    }
    float wa[9], wb[9];
#pragma unroll
    for (int t = 0; t < 9; t++) {
        wa[t] = w1t[(size_t)ch * 9 + t];
        wb[t] = w2t[(size_t)ch * 9 + t];
    }
    __syncthreads();
    // pe1 rows i=0..9 (y=y0-1+i), cols c1=0..129 (x=c1-1); zero outside image (2nd conv zero-pads pe1)
    for (int idx = threadIdx.x; idx < 10 * 130; idx += 256) {
        int i = idx / 130, c1 = idx % 130;
        int yy = y0 - 1 + i, xx = c1 - 1;
        float val = 0.f;
        if (yy >= 0 && yy < HH && xx >= 0 && xx < WW) {
            float a = wa[0] * t1[i][c1]     + wa[1] * t1[i][c1 + 1]     + wa[2] * t1[i][c1 + 2]
                    + wa[3] * t1[i + 1][c1] + wa[4] * t1[i + 1][c1 + 1] + wa[5] * t1[i + 1][c1 + 2]
                    + wa[6] * t1[i + 2][c1] + wa[7] * t1[i + 2][c1 + 1] + wa[8] * t1[i + 2][c1 + 2];
            val = 0.5f * a * (1.0f + erff(a * 0.70710678118654752f));
        }
        t2[i][c1] = val;
    }
    __syncthreads();
    int x = threadIdx.x & 127;
    int half = threadIdx.x >> 7;
    bf16_t* oplane = pe2 + (size_t)b * 4194304 + (size_t)ch * NTOK;
#pragma unroll
    for (int rp = 0; rp < 4; rp++) {
        int r = rp * 2 + half;
        float acc = wb[0] * t2[r][x]     + wb[1] * t2[r][x + 1]     + wb[2] * t2[r][x + 2]
                  + wb[3] * t2[r + 1][x] + wb[4] * t2[r + 1][x + 1] + wb[5] * t2[r + 1][x + 2]
                  + wb[6] * t2[r + 2][x] + wb[7] * t2[r + 2][x + 1] + wb[8] * t2[r + 2][x + 2];
        oplane[(size_t)(y0 + r) * WW + x] = f2bf(acc);
    }
}

extern "C" void kernel_launch(void* const* d_in, const int* in_sizes, int n_in,
                              void* d_out, int out_size, void* d_ws, size_t ws_size,
                              hipStream_t stream) {
    const float* x_in    = (const float*)d_in[0];
    const float* wq      = (const float*)d_in[1];
    const float* wk      = (const float*)d_in[2];
    const float* wv      = (const float*)d_in[3];
    const float* qg      = (const float*)d_in[4];
    const float* qb      = (const float*)d_in[5];
    const float* qm      = (const float*)d_in[6];
    const float* qv      = (const float*)d_in[7];
    const float* kg      = (const float*)d_in[8];
    const float* kb      = (const float*)d_in[9];
    const float* km      = (const float*)d_in[10];
    const float* kv_     = (const float*)d_in[11];
    const float* vg      = (const float*)d_in[12];
    const float* vb      = (const float*)d_in[13];
    const float* vm      = (const float*)d_in[14];
    const float* vv      = (const float*)d_in[15];
    const float* rescale = (const float*)d_in[16];
    const float* proj_w  = (const float*)d_in[17];
    const float* proj_b  = (const float*)d_in[18];
    const float* pos_w1  = (const float*)d_in[19];
    const float* pos_w2  = (const float*)d_in[20];

    char* ws = (char*)d_ws;
    bf16_t* vt   = (bf16_t*)(ws + OFF_VT);
    bf16_t* xo   = (bf16_t*)(ws + OFF_XO);
    bf16_t* vp   = (bf16_t*)(ws + OFF_VP);
    bf16_t* pe2  = (bf16_t*)(ws + OFF_PE2);
    bf16_t* wbf  = (bf16_t*)(ws + OFF_WBF);
    float* S     = (float*)(ws + OFF_S);
    float* ssq   = (float*)(ws + OFF_SSQ);
    float* ssk   = (float*)(ws + OFF_SSK);

    hipMemsetAsync(ws + OFF_S, 0, (size_t)540672, stream);

    k12_fused<<<dim3(16, 16, 2), 512, 0, stream>>>(x_in, wq, wk, wv,
                                                   qg, qb, qm, qv,
                                                   kg, kb, km, kv_,
                                                   vg, vb, vm, vv,
                                                   vt, S, ssq, ssk);
    k3_softmax<<<dim3(32), 64, 0, stream>>>(S, ssq, ssk, rescale);
    cvt_w<<<dim3(256), 256, 0, stream>>>(proj_w, wbf);
    k4_mfma<<<dim3(128, 16, 2), 256, 0, stream>>>(S, vt, xo);
    // k6: vp[co][t] = W[co][:] . vt[t][:]          (M=256,N=16384,K=1024)
    gemm_tn<0><<<dim3(2, 128, 2), 256, 0, stream>>>(wbf, vt, proj_b, vp,
                                                    1024, 1024, 16384, 1024,
                                                    0L, 16777216L, 4194304L, 0, nullptr);
    k_pos_fused<<<dim3(16, 256, 2), 256, 0, stream>>>(vp, pos_w1, pos_w2, pe2);
    // k5': out[t][co] = xo_flat[t][:] . W[co][:] + bias + pe2[co][t]  (f32, k9 fused)
    gemm_tn<1><<<dim3(128, 2, 2), 256, 0, stream>>>(xo, wbf, proj_b, d_out,
                                                    1024, 1024, 256, 1024,
                                                    16777216L, 0L, 4194304L, 1, pe2);
}